// Round 16
// baseline (171.587 us; speedup 1.0000x reference)
//
#include <hip/hip_runtime.h>
#include <hip/hip_cooperative_groups.h>

namespace cg = cooperative_groups;

// D-FINE post-processor, cooperative single dispatch:
//   Phase 1 (all 2048 blocks x 256 thr, 8 blocks/CU streaming geometry):
//     block (b,s) filters slice s (2500 float4) of batch b; hits (logit > THR)
//     -> private global segment candG[blk*seg ..] via LDS-counter offsets;
//     count -> scnt[blk]. Race-free, no device atomics, no memset.
//   grid.sync()  (cooperative launch; ordering + visibility)
//   Phase 2 (blocks 0..B-1): selector for batch b = blk. Prefix-sum 8 segment
//     counts, bound-check (m_s <= seg, K <= tot <= CAPL), segments -> LDS,
//     rank-based selection (count-of-greater on packed (key<<32)|~idx = exact
//     jax.lax.top_k tie semantics), decode boxes, emit. Exact histogram
//     FALLBACK over the batch if the bound check fails.
//   Host: if hipLaunchCooperativeKernel errors, launch the validated R10-style
//     fused kernel instead (deterministic per environment).
// Output (float32): labels [B*K] | boxes [B*K*4] | scores [B*K]

constexpr int   NT1   = 256;    // coop block
constexpr int   BPB   = 8;      // slices/segments per batch
constexpr int   SEG   = 512;    // slots per segment (expect ~62 hits)
constexpr int   CAPL  = 2048;   // selector LDS candidate cap (16 KB)
constexpr int   NTF   = 1024;   // fallback fused kernel block
constexpr int   CAPF  = 4096;   // fallback kernel LDS cap
constexpr int   NBINS = 4096;
constexpr float THR   = 2.5f;   // static pre-filter (fallback makes it safe)

__device__ __forceinline__ unsigned f2key(float f) {
    unsigned u = __float_as_uint(f);
    return (u & 0x80000000u) ? ~u : (u | 0x80000000u);
}
__device__ __forceinline__ float key2f(unsigned k) {
    unsigned u = (k & 0x80000000u) ? (k & 0x7FFFFFFFu) : ~k;
    return __uint_as_float(u);
}
__device__ __forceinline__ unsigned long long packkv(unsigned key, unsigned idx) {
    return ((unsigned long long)key << 32) | (unsigned long long)(0xFFFFFFFFu - idx);
}

// ======================= cooperative kernel =======================
__global__ __launch_bounds__(NT1, 8) void dfine_coop_kernel(
    const float* __restrict__ logits,        // [B, Q*C]
    const float* __restrict__ pboxes,        // [B, Q, 4]
    const float* __restrict__ sizes,         // [B, 2]
    unsigned* __restrict__ scnt,             // [B*BPB] (overwritten each call)
    unsigned long long* __restrict__ candG,  // [B*BPB*seg]
    float* __restrict__ out,
    int B, int Q, int C, int K, int N4, int chunk4, int seg)
{
    const int blk = blockIdx.x;
    const int tid = threadIdx.x;
    const int N   = Q * C;

    __shared__ unsigned long long candS[CAPL];   // 16 KB (selector; hist overlays)
    __shared__ unsigned partial[NT1];
    __shared__ unsigned msz[BPB], moff[BPB];
    __shared__ unsigned lcnt, candCount, threshBin;
    __shared__ int hot;

    // ---------- phase 1: filter my slice (pure TLP streaming) ----------
    {
        const int fb = blk >> 3;                 // batch
        const int fs = blk & 7;                  // slice
        const int lo = fs * chunk4;
        const int hi = (lo + chunk4 < N4) ? (lo + chunk4) : N4;
        const float4* __restrict__ base4 =
            reinterpret_cast<const float4*>(logits + (long long)fb * N);
        unsigned long long* __restrict__ segp = candG + (long long)blk * seg;

        if (tid == 0) lcnt = 0u;
        __syncthreads();
        for (int i4 = lo + tid; i4 < hi; i4 += NT1) {
            float4 v = base4[i4];
            float mx = fmaxf(fmaxf(v.x, v.y), fmaxf(v.z, v.w));
            if (mx > THR) {
                unsigned bi = (unsigned)(4 * i4);
                if (v.x > THR) { unsigned p = atomicAdd(&lcnt, 1u);
                    if (p < (unsigned)seg) segp[p] = packkv(f2key(v.x), bi + 0); }
                if (v.y > THR) { unsigned p = atomicAdd(&lcnt, 1u);
                    if (p < (unsigned)seg) segp[p] = packkv(f2key(v.y), bi + 1); }
                if (v.z > THR) { unsigned p = atomicAdd(&lcnt, 1u);
                    if (p < (unsigned)seg) segp[p] = packkv(f2key(v.z), bi + 2); }
                if (v.w > THR) { unsigned p = atomicAdd(&lcnt, 1u);
                    if (p < (unsigned)seg) segp[p] = packkv(f2key(v.w), bi + 3); }
            }
        }
        __syncthreads();
        if (tid == 0) scnt[blk] = lcnt;          // true count (> seg => fallback)
    }

    cg::this_grid().sync();                      // execution + memory ordering

    if (blk >= B) return;
    const int b = blk;                           // selector for batch b

    // ---------- phase 2: select + emit ----------
    if (tid < BPB) msz[tid] = scnt[b * BPB + tid];
    __syncthreads();
    if (tid == 0) {
        unsigned tot = 0; int ok = 1;
        #pragma unroll
        for (int s = 0; s < BPB; ++s) {
            moff[s] = tot;
            if (msz[s] > (unsigned)seg) ok = 0;
            tot += msz[s];
        }
        candCount = tot;
        hot = ok && tot >= (unsigned)K && tot <= (unsigned)CAPL;
    }
    __syncthreads();

    int n;
    if (hot) {
        n = (int)candCount;
        #pragma unroll
        for (int s = 0; s < BPB; ++s) {
            const unsigned long long* sp = candG + (long long)(b * BPB + s) * seg;
            unsigned m = msz[s], o = moff[s];
            for (unsigned i = tid; i < m; i += NT1) candS[o + i] = sp[i];
        }
        __syncthreads();
    } else {
        // ---- fallback: exact histogram selection over the full batch ----
        unsigned* hist = reinterpret_cast<unsigned*>(candS);   // 4096*4B = 16 KB
        const float* __restrict__ lg = logits + (long long)b * N;
        for (int i = tid; i < NBINS; i += NT1) hist[i] = 0u;
        if (tid == 0) candCount = 0u;
        __syncthreads();
        for (int i = tid; i < N; i += NT1)
            atomicAdd(&hist[f2key(lg[i]) >> 20], 1u);
        __syncthreads();
        {
            const int BPT = NBINS / NT1;                 // 16
            unsigned s = 0;
            #pragma unroll
            for (int m = 0; m < BPT; ++m) s += hist[tid * BPT + m];
            partial[tid] = s;
        }
        __syncthreads();
        if (tid < 64) {
            const int PPG = NT1 / 64;                    // 4
            unsigned gs = 0;
            #pragma unroll
            for (int m = 0; m < PPG; ++m) gs += partial[tid * PPG + m];
            unsigned pre = gs;
            #pragma unroll
            for (int off = 1; off < 64; off <<= 1) {
                unsigned t = __shfl_up(pre, off);
                if (tid >= off) pre += t;
            }
            unsigned total = __shfl(pre, 63);
            unsigned suf   = total - (pre - gs);
            unsigned long long m1 = __ballot(suf >= (unsigned)K);
            int g = 63 - __clzll(m1);
            unsigned above = total - __shfl(pre, g);
            unsigned hv = hist[g * 64 + tid];
            unsigned pre2 = hv;
            #pragma unroll
            for (int off = 1; off < 64; off <<= 1) {
                unsigned t = __shfl_up(pre2, off);
                if (tid >= off) pre2 += t;
            }
            unsigned total2 = __shfl(pre2, 63);
            unsigned suf2   = above + total2 - (pre2 - hv);
            unsigned long long m2 = __ballot(suf2 >= (unsigned)K);
            int l2 = 63 - __clzll(m2);
            if (tid == 0) threshBin = (unsigned)(g * 64 + l2);
        }
        __syncthreads();
        const unsigned tb = threshBin;
        __syncthreads();
        for (int i = tid; i < N; i += NT1) {
            unsigned k = f2key(lg[i]);
            if ((k >> 20) >= tb) {
                unsigned p = atomicAdd(&candCount, 1u);
                if (p < (unsigned)CAPL) candS[p] = packkv(k, (unsigned)i);
            }
        }
        __syncthreads();
        n = (int)min(candCount, (unsigned)CAPL);
    }

    // rank-based selection + emit
    const int BK = B * K;
    float* __restrict__ out_labels = out;
    float* __restrict__ out_boxes  = out + BK;
    float* __restrict__ out_scores = out + (long long)BK * 5;
    const float s0 = sizes[2 * b];
    const float s1 = sizes[2 * b + 1];

    for (int t = tid; t < n; t += NT1) {
        unsigned long long my = candS[t];
        int r = 0;
        for (int j = 0; j < n; ++j) r += (candS[j] > my);  // packed keys unique
        if (r < K) {
            unsigned key = (unsigned)(my >> 32);
            unsigned idx = 0xFFFFFFFFu - (unsigned)(my & 0xFFFFFFFFull);
            float logit = key2f(key);
            float score = 1.0f / (1.0f + expf(-logit));
            int label = (int)(idx % (unsigned)C);
            int q     = (int)(idx / (unsigned)C);
            float4 bp = *reinterpret_cast<const float4*>(pboxes + ((long long)b * Q + q) * 4);
            int o = b * K + r;
            out_labels[o] = (float)label;
            out_scores[o] = score;
            float4 bb;
            bb.x = (bp.x - 0.5f * bp.z) * s0;
            bb.y = (bp.y - 0.5f * bp.w) * s1;
            bb.z = (bp.x + 0.5f * bp.z) * s0;
            bb.w = (bp.y + 0.5f * bp.w) * s1;
            *reinterpret_cast<float4*>(out_boxes + 4LL * o) = bb;
        }
    }
}

// ============ fallback: validated R10-style fused kernel ============
__device__ __forceinline__ void fconsume1(
    float x, unsigned idx, unsigned* lcnt, unsigned long long* cand)
{
    if (x > THR) {
        unsigned p = atomicAdd(lcnt, 1u);
        if (p < (unsigned)CAPF) cand[p] = packkv(f2key(x), idx);
    }
}
__device__ __forceinline__ void fconsume4(
    float4 v, int i4, int N4, unsigned* lcnt, unsigned long long* cand)
{
    if (i4 < N4) {
        float mx = fmaxf(fmaxf(v.x, v.y), fmaxf(v.z, v.w));
        if (mx > THR) {
            unsigned bi = (unsigned)(4 * i4);
            fconsume1(v.x, bi + 0, lcnt, cand);
            fconsume1(v.y, bi + 1, lcnt, cand);
            fconsume1(v.z, bi + 2, lcnt, cand);
            fconsume1(v.w, bi + 3, lcnt, cand);
        }
    }
}
template<int UNROLL>
__device__ __forceinline__ void ffilter_phase(
    const float4* __restrict__ base4, int start, int N4,
    unsigned* lcnt, unsigned long long* cand, int tid)
{
    float4 v[UNROLL];
    #pragma unroll
    for (int j = 0; j < UNROLL; ++j) {
        int i4 = start + j * NTF + tid;
        v[j] = base4[(i4 < N4) ? i4 : (N4 - 1)];
    }
    __builtin_amdgcn_sched_barrier(0);
    #pragma unroll
    for (int j = 0; j < UNROLL; ++j)
        fconsume4(v[j], start + j * NTF + tid, N4, lcnt, cand);
}

__global__ __launch_bounds__(NTF) void dfine_fused_kernel(
    const float* __restrict__ logits, const float* __restrict__ pboxes,
    const float* __restrict__ sizes, float* __restrict__ out,
    int B, int Q, int C, int K)
{
    const int b   = blockIdx.x;
    const int tid = threadIdx.x;
    const int N   = Q * C;
    const int N4  = N >> 2;
    const float4* __restrict__ base4 = reinterpret_cast<const float4*>(logits + (long long)b * N);

    __shared__ unsigned long long cand[CAPF];
    __shared__ unsigned hist[NBINS];
    __shared__ unsigned partial[NTF];
    __shared__ unsigned lcnt, candCount, threshBin;

    if (tid == 0) lcnt = 0u;
    __syncthreads();

    ffilter_phase<7>(base4, 0,        N4, &lcnt, cand, tid);
    ffilter_phase<7>(base4, 7 * NTF,  N4, &lcnt, cand, tid);
    ffilter_phase<6>(base4, 14 * NTF, N4, &lcnt, cand, tid);
    for (int i4 = 20 * NTF + tid; i4 < N4; i4 += NTF)
        fconsume4(base4[i4], i4, N4, &lcnt, cand);
    __syncthreads();

    int n;
    const unsigned tot = lcnt;
    if (tot >= (unsigned)K && tot <= (unsigned)CAPF) {
        n = (int)tot;
    } else {
        const float* __restrict__ lg = logits + (long long)b * N;
        for (int i = tid; i < NBINS; i += NTF) hist[i] = 0u;
        if (tid == 0) candCount = 0u;
        __syncthreads();
        for (int i = tid; i < N; i += NTF)
            atomicAdd(&hist[f2key(lg[i]) >> 20], 1u);
        __syncthreads();
        {
            const int BPT = NBINS / NTF;
            unsigned s = 0;
            #pragma unroll
            for (int m = 0; m < BPT; ++m) s += hist[tid * BPT + m];
            partial[tid] = s;
        }
        __syncthreads();
        if (tid < 64) {
            const int PPG = NTF / 64;
            unsigned gs = 0;
            #pragma unroll
            for (int m = 0; m < PPG; ++m) gs += partial[tid * PPG + m];
            unsigned pre = gs;
            #pragma unroll
            for (int off = 1; off < 64; off <<= 1) {
                unsigned t = __shfl_up(pre, off);
                if (tid >= off) pre += t;
            }
            unsigned total = __shfl(pre, 63);
            unsigned suf   = total - (pre - gs);
            unsigned long long m1 = __ballot(suf >= (unsigned)K);
            int g = 63 - __clzll(m1);
            unsigned above = total - __shfl(pre, g);
            unsigned hv = hist[g * 64 + tid];
            unsigned pre2 = hv;
            #pragma unroll
            for (int off = 1; off < 64; off <<= 1) {
                unsigned t = __shfl_up(pre2, off);
                if (tid >= off) pre2 += t;
            }
            unsigned total2 = __shfl(pre2, 63);
            unsigned suf2   = above + total2 - (pre2 - hv);
            unsigned long long m2 = __ballot(suf2 >= (unsigned)K);
            int l2 = 63 - __clzll(m2);
            if (tid == 0) threshBin = (unsigned)(g * 64 + l2);
        }
        __syncthreads();
        const unsigned tb = threshBin;
        for (int i = tid; i < N; i += NTF) {
            unsigned k = f2key(lg[i]);
            if ((k >> 20) >= tb) {
                unsigned p = atomicAdd(&candCount, 1u);
                if (p < (unsigned)CAPF) cand[p] = packkv(k, (unsigned)i);
            }
        }
        __syncthreads();
        n = (int)min(candCount, (unsigned)CAPF);
    }

    const int BK = B * K;
    float* __restrict__ out_labels = out;
    float* __restrict__ out_boxes  = out + BK;
    float* __restrict__ out_scores = out + (long long)BK * 5;
    const float s0 = sizes[2 * b];
    const float s1 = sizes[2 * b + 1];

    for (int t = tid; t < n; t += NTF) {
        unsigned long long my = cand[t];
        int r = 0;
        for (int j = 0; j < n; ++j) r += (cand[j] > my);
        if (r < K) {
            unsigned key = (unsigned)(my >> 32);
            unsigned idx = 0xFFFFFFFFu - (unsigned)(my & 0xFFFFFFFFull);
            float logit = key2f(key);
            float score = 1.0f / (1.0f + expf(-logit));
            int label = (int)(idx % (unsigned)C);
            int q     = (int)(idx / (unsigned)C);
            float4 bp = *reinterpret_cast<const float4*>(pboxes + ((long long)b * Q + q) * 4);
            int o = b * K + r;
            out_labels[o] = (float)label;
            out_scores[o] = score;
            float4 bb;
            bb.x = (bp.x - 0.5f * bp.z) * s0;
            bb.y = (bp.y - 0.5f * bp.w) * s1;
            bb.z = (bp.x + 0.5f * bp.z) * s0;
            bb.w = (bp.y + 0.5f * bp.w) * s1;
            *reinterpret_cast<float4*>(out_boxes + 4LL * o) = bb;
        }
    }
}

extern "C" void kernel_launch(void* const* d_in, const int* in_sizes, int n_in,
                              void* d_out, int out_size, void* d_ws, size_t ws_size,
                              hipStream_t stream) {
    const float* logits = (const float*)d_in[0];
    const float* pboxes = (const float*)d_in[1];
    const float* sizes  = (const float*)d_in[2];

    const int B = in_sizes[2] / 2;                 // 256
    const int Q = in_sizes[1] / (4 * B);           // 1000
    const int C = in_sizes[0] / (B * Q);           // 80
    const int K = out_size / (6 * B);              // 300
    const int N = Q * C;
    int N4 = N / 4;
    int chunk4 = (N4 + BPB - 1) / BPB;             // 2500
    const int NSEGS = B * BPB;                     // 2048

    // workspace: scnt[B*BPB] | candG[B*BPB*seg]   (no zeroing required)
    unsigned* scnt = (unsigned*)d_ws;
    size_t cand_off = (((size_t)NSEGS * sizeof(unsigned) + 255) & ~(size_t)255);
    unsigned long long* candG = (unsigned long long*)((char*)d_ws + cand_off);
    long long avail = (long long)ws_size - (long long)cand_off;
    int seg = (avail > 0) ? (int)(avail / ((long long)NSEGS * 8)) : 0;
    if (seg > SEG) seg = SEG;
    if (seg < 0) seg = 0;

    float* outp = (float*)d_out;
    void* args[] = { (void*)&logits, (void*)&pboxes, (void*)&sizes,
                     (void*)&scnt, (void*)&candG, (void*)&outp,
                     (void*)&B, (void*)&Q, (void*)&C, (void*)&K,
                     (void*)&N4, (void*)&chunk4, (void*)&seg };

    hipError_t e = hipLaunchCooperativeKernel(
        (const void*)dfine_coop_kernel, dim3(NSEGS), dim3(NT1), args, 0, stream);
    if (e != hipSuccess) {
        (void)hipGetLastError();                   // clear sticky error
        dfine_fused_kernel<<<B, NTF, 0, stream>>>(
            logits, pboxes, sizes, outp, B, Q, C, K);
    }
}

// Round 17
// 30.602 us; speedup vs baseline: 5.6070x; 5.6070x over previous
//
#include <hip/hip_runtime.h>
#include <cstdint>

// D-FINE post-processor, SINGLE fused kernel: one block per batch (256 x 1024).
//   Filter: per-wave global_load_lds DMA pipeline (HBM -> LDS direct, no
//     VGPR-return path). Triple-buffered 32 KB chunks; each wave DMAs and
//     consumes ONLY its own 2 KB slice per chunk -> no __syncthreads in the
//     pipeline. Counted s_waitcnt vmcnt(4/2/0) + sched_barrier(0) fences
//     (compiler would otherwise hoist the ds_reads past the asm waitcnt).
//     Hits (logit > THR) compact into LDS cand[] via an LDS counter.
//     {x > THR} is a prefix of the descending order, so if K <= n <= CAPL the
//     top-K is provably contained.
//   Select (R10): rank-based selection (count-of-greater over packed
//     (key<<32)|~idx keys = exact jax.lax.top_k tie semantics, broadcast LDS
//     reads), scatter-emit by rank.
//   Fallback: exact histogram selection (hist/partial overlay the DMA buffers,
//     which are drained by then) if the bound check fails.
// Output (float32): labels [B*K] | boxes [B*K*4] | scores [B*K]

constexpr int   NT     = 1024;
constexpr int   NBINS  = 4096;
constexpr int   CAPL   = 4096;   // LDS candidate capacity
constexpr int   CHUNK4 = 2048;   // float4s per DMA chunk (32 KB)
constexpr int   NBUF   = 3;      // triple buffer
constexpr float THR    = 2.5f;   // static pre-filter (fallback makes it safe)

__device__ __forceinline__ unsigned f2key(float f) {
    unsigned u = __float_as_uint(f);
    return (u & 0x80000000u) ? ~u : (u | 0x80000000u);
}
__device__ __forceinline__ float key2f(unsigned k) {
    unsigned u = (k & 0x80000000u) ? (k & 0x7FFFFFFFu) : ~k;
    return __uint_as_float(u);
}
__device__ __forceinline__ unsigned long long packkv(unsigned key, unsigned idx) {
    return ((unsigned long long)key << 32) | (unsigned long long)(0xFFFFFFFFu - idx);
}

// HBM -> LDS direct DMA, 16 B per lane. LDS dest is wave-uniform base + lane*16;
// global src is per-lane. vmcnt-tracked, no VGPR writeback.
typedef const __attribute__((address_space(1))) unsigned g_u32;
typedef __attribute__((address_space(3))) unsigned l_u32;
__device__ __forceinline__ void gload_lds16(const void* g, void* l) {
    __builtin_amdgcn_global_load_lds((g_u32*)g, (l_u32*)l, 16, 0, 0);
}

__device__ __forceinline__ void consume1(
    float x, unsigned idx, unsigned* lcnt, unsigned long long* cand)
{
    if (x > THR) {
        unsigned p = atomicAdd(lcnt, 1u);
        if (p < (unsigned)CAPL) cand[p] = packkv(f2key(x), idx);
    }
}
__device__ __forceinline__ void consume4(
    float4 v, int i4, int N4, unsigned* lcnt, unsigned long long* cand)
{
    if (i4 < N4) {
        float mx = fmaxf(fmaxf(v.x, v.y), fmaxf(v.z, v.w));
        if (mx > THR) {
            unsigned bi = (unsigned)(4 * i4);
            consume1(v.x, bi + 0, lcnt, cand);
            consume1(v.y, bi + 1, lcnt, cand);
            consume1(v.z, bi + 2, lcnt, cand);
            consume1(v.w, bi + 3, lcnt, cand);
        }
    }
}

__global__ __launch_bounds__(NT) void dfine_fused_kernel(
    const float* __restrict__ logits,   // [B, Q*C]
    const float* __restrict__ pboxes,   // [B, Q, 4]  (cx, cy, w, h)
    const float* __restrict__ sizes,    // [B, 2]
    float* __restrict__ out,            // labels | boxes | scores
    int B, int Q, int C, int K)
{
    const int b   = blockIdx.x;
    const int tid = threadIdx.x;
    const int w   = tid >> 6;           // wave id (0..15)
    const int l   = tid & 63;           // lane id
    const int N   = Q * C;
    const int N4  = N >> 2;             // N divisible by 4 (C=80)
    const float4* __restrict__ base4 = reinterpret_cast<const float4*>(logits + (long long)b * N);

    __shared__ alignas(16) char dmabuf[NBUF][CHUNK4 * 16];  // 96 KB
    __shared__ unsigned long long cand[CAPL];               // 32 KB
    __shared__ unsigned lcnt;
    __shared__ unsigned candCount;
    __shared__ unsigned threshBin;

    if (tid == 0) lcnt = 0u;
    __syncthreads();

    // ---- filter: per-wave DMA pipeline, no barriers ----
    {
        const int NCH = (N4 + CHUNK4 - 1) / CHUNK4;         // 10 at N4=20000

        auto issue = [&](int c) {
            if (c >= NCH) return;
            char* lb = &dmabuf[c % NBUF][(w * 128) * 16];   // wave-uniform base
            int bi4 = c * CHUNK4 + w * 128;
            #pragma unroll
            for (int inst = 0; inst < 2; ++inst) {
                int i4 = bi4 + inst * 64 + l;
                gload_lds16(base4 + ((i4 < N4) ? i4 : (N4 - 1)), lb + inst * 1024);
            }
        };

        issue(0); issue(1); issue(2);
        __builtin_amdgcn_sched_barrier(0);
        for (int c = 0; c < NCH; ++c) {
            // wait for chunk c's 2 DMAs (this wave's): outstanding after = 2*(inflight-1)
            if (c + 2 < NCH)      asm volatile("s_waitcnt vmcnt(4)" ::: "memory");
            else if (c + 1 < NCH) asm volatile("s_waitcnt vmcnt(2)" ::: "memory");
            else                  asm volatile("s_waitcnt vmcnt(0)" ::: "memory");
            __builtin_amdgcn_sched_barrier(0);              // rule #18: pin ds_reads
            const char* lb = &dmabuf[c % NBUF][(w * 128) * 16];
            float4 v0 = *reinterpret_cast<const float4*>(lb + l * 16);
            float4 v1 = *reinterpret_cast<const float4*>(lb + (64 + l) * 16);
            int i40 = c * CHUNK4 + w * 128 + l;
            consume4(v0, i40,      N4, &lcnt, cand);
            consume4(v1, i40 + 64, N4, &lcnt, cand);
            __builtin_amdgcn_sched_barrier(0);              // consume before reuse
            issue(c + 3);                                   // buffer (c%NBUF) now free
            __builtin_amdgcn_sched_barrier(0);
        }
    }
    __syncthreads();

    int n;
    const unsigned tot = lcnt;
    if (tot >= (unsigned)K && tot <= (unsigned)CAPL) {
        n = (int)tot;                               // hot path: cand[] already in LDS
    } else {
        // ---- fallback: exact histogram selection (overlays drained DMA bufs) ----
        unsigned* hist    = reinterpret_cast<unsigned*>(&dmabuf[0][0]);   // 16 KB
        unsigned* partial = hist + NBINS;                                 //  4 KB
        const float* __restrict__ lg = logits + (long long)b * N;
        for (int i = tid; i < NBINS; i += NT) hist[i] = 0u;
        if (tid == 0) candCount = 0u;
        __syncthreads();
        for (int i = tid; i < N; i += NT)
            atomicAdd(&hist[f2key(lg[i]) >> 20], 1u);
        __syncthreads();
        {
            const int BPT = NBINS / NT;
            unsigned s = 0;
            #pragma unroll
            for (int m = 0; m < BPT; ++m) s += hist[tid * BPT + m];
            partial[tid] = s;
        }
        __syncthreads();
        if (tid < 64) {
            const int PPG = NT / 64;
            unsigned gs = 0;
            #pragma unroll
            for (int m = 0; m < PPG; ++m) gs += partial[tid * PPG + m];
            unsigned pre = gs;
            #pragma unroll
            for (int off = 1; off < 64; off <<= 1) {
                unsigned t = __shfl_up(pre, off);
                if (tid >= off) pre += t;
            }
            unsigned total = __shfl(pre, 63);
            unsigned suf   = total - (pre - gs);
            unsigned long long m1 = __ballot(suf >= (unsigned)K);
            int g = 63 - __clzll(m1);
            unsigned above = total - __shfl(pre, g);
            unsigned hv = hist[g * 64 + tid];
            unsigned pre2 = hv;
            #pragma unroll
            for (int off = 1; off < 64; off <<= 1) {
                unsigned t = __shfl_up(pre2, off);
                if (tid >= off) pre2 += t;
            }
            unsigned total2 = __shfl(pre2, 63);
            unsigned suf2   = above + total2 - (pre2 - hv);
            unsigned long long m2 = __ballot(suf2 >= (unsigned)K);
            int l2 = 63 - __clzll(m2);
            if (tid == 0) threshBin = (unsigned)(g * 64 + l2);
        }
        __syncthreads();
        const unsigned tb = threshBin;
        for (int i = tid; i < N; i += NT) {
            unsigned k = f2key(lg[i]);
            if ((k >> 20) >= tb) {
                unsigned p = atomicAdd(&candCount, 1u);
                if (p < (unsigned)CAPL) cand[p] = packkv(k, (unsigned)i);
            }
        }
        __syncthreads();
        n = (int)min(candCount, (unsigned)CAPL);
    }

    // ---- rank-based selection + emit ----
    const int BK = B * K;
    float* __restrict__ out_labels = out;
    float* __restrict__ out_boxes  = out + BK;
    float* __restrict__ out_scores = out + (long long)BK * 5;
    const float s0 = sizes[2 * b];
    const float s1 = sizes[2 * b + 1];

    for (int t = tid; t < n; t += NT) {
        unsigned long long my = cand[t];
        int r = 0;
        for (int j = 0; j < n; ++j) r += (cand[j] > my);   // packed keys unique
        if (r < K) {
            unsigned key = (unsigned)(my >> 32);
            unsigned idx = 0xFFFFFFFFu - (unsigned)(my & 0xFFFFFFFFull);
            float logit = key2f(key);
            float score = 1.0f / (1.0f + expf(-logit));
            int label = (int)(idx % (unsigned)C);
            int q     = (int)(idx / (unsigned)C);
            float4 bp = *reinterpret_cast<const float4*>(pboxes + ((long long)b * Q + q) * 4);
            int o = b * K + r;
            out_labels[o] = (float)label;
            out_scores[o] = score;
            float4 bb;
            bb.x = (bp.x - 0.5f * bp.z) * s0;
            bb.y = (bp.y - 0.5f * bp.w) * s1;
            bb.z = (bp.x + 0.5f * bp.z) * s0;
            bb.w = (bp.y + 0.5f * bp.w) * s1;
            *reinterpret_cast<float4*>(out_boxes + 4LL * o) = bb;
        }
    }
}

extern "C" void kernel_launch(void* const* d_in, const int* in_sizes, int n_in,
                              void* d_out, int out_size, void* d_ws, size_t ws_size,
                              hipStream_t stream) {
    const float* logits = (const float*)d_in[0];
    const float* pboxes = (const float*)d_in[1];
    const float* sizes  = (const float*)d_in[2];

    const int B = in_sizes[2] / 2;                 // 256
    const int Q = in_sizes[1] / (4 * B);           // 1000
    const int C = in_sizes[0] / (B * Q);           // 80
    const int K = out_size / (6 * B);              // 300

    dfine_fused_kernel<<<B, NT, 0, stream>>>(
        logits, pboxes, sizes, (float*)d_out, B, Q, C, K);
}